// Round 1
// baseline (373.145 us; speedup 1.0000x reference)
//
#include <hip/hip_runtime.h>
#include <hip/hip_bf16.h>

#define B_ 256
#define D_ 2048
#define N_ 30000
#define INV_TEMP 20.0f
#define MOM 0.2f
#define EPSF 1e-12f
#define BN 48
#define KC 64
#define NT 625   // 30000 / 48

typedef __attribute__((ext_vector_type(8))) short bf16x8;
typedef __attribute__((ext_vector_type(4))) float f32x4;

__device__ __forceinline__ unsigned short f2bf(float f) {
  union { float f; unsigned int u; } v; v.f = f;
  unsigned int u = v.u;
  unsigned int r = (u + 0x7fffu + ((u >> 16) & 1u)) >> 16;
  return (unsigned short)r;
}

__device__ __forceinline__ float blockReduceSum256(float v) {
  __shared__ float red[4];
  #pragma unroll
  for (int m = 32; m >= 1; m >>= 1) v += __shfl_xor(v, m, 64);
  int lane = threadIdx.x & 63, w = threadIdx.x >> 6;
  __syncthreads();
  if (lane == 0) red[w] = v;
  __syncthreads();
  return red[0] + red[1] + red[2] + red[3];
}

// ---------------- Kernel A: normalize inputs, emit fp32 + bf16 copies -------
__global__ __launch_bounds__(256) void knorm(const float* __restrict__ in,
                                             float* __restrict__ x,
                                             unsigned short* __restrict__ xbf) {
  int b = blockIdx.x, t = threadIdx.x;
  const float* row = in + (size_t)b * D_;
  float vals[8]; float ss = 0.f;
  #pragma unroll
  for (int i = 0; i < 8; i++) { float f = row[t + i * 256]; vals[i] = f; ss += f * f; }
  float tot = blockReduceSum256(ss);
  float inv = 1.0f / (sqrtf(tot) + EPSF);
  #pragma unroll
  for (int i = 0; i < 8; i++) {
    float xv = vals[i] * inv;
    x[(size_t)b * D_ + t + i * 256] = xv;
    xbf[(size_t)b * D_ + t + i * 256] = f2bf(xv);
  }
}

// ---------------- Kernel B: bf16 MFMA GEMM + partial logsumexp + bank copy --
__global__ __launch_bounds__(256) void kmain(const float* __restrict__ feats,
                                             const unsigned short* __restrict__ xbf,
                                             float* __restrict__ outF,
                                             float* __restrict__ pmax,
                                             float* __restrict__ psum) {
  __shared__ __align__(16) unsigned short xs[256 * KC];  // 32 KB, swizzled
  __shared__ __align__(16) unsigned short fs[BN * KC];   // 6 KB, swizzled
  int tid = threadIdx.x;
  int wave = tid >> 6, lane = tid & 63;
  int n0 = blockIdx.x * BN;

  f32x4 acc[4][3];
  #pragma unroll
  for (int i = 0; i < 4; i++)
    #pragma unroll
    for (int j = 0; j < 3; j++) acc[i][j] = f32x4{0.f, 0.f, 0.f, 0.f};

  for (int k0 = 0; k0 < D_; k0 += KC) {
    __syncthreads();
    // stage x tile: 256 rows x 64 cols (bf16), 16B per thread-iter
    #pragma unroll
    for (int i = 0; i < 8; i++) {
      int fi = tid + i * 256;
      int b = fi >> 3, g = fi & 7;
      uint4 v = *(const uint4*)(xbf + (size_t)b * D_ + k0 + g * 8);
      int byte = b * 128 + ((g * 16) ^ ((b & 7) << 4));
      *(uint4*)((char*)xs + byte) = v;
    }
    // stage f tile: 48 rows x 64 cols fp32 -> bf16, fused copy to out
    #pragma unroll
    for (int i = 0; i < 3; i++) {
      int fi = tid + i * 256;
      int n = fi >> 4, kk = (fi & 15) * 4;
      int row = n0 + n;
      const float4 v = *(const float4*)(feats + (size_t)row * D_ + k0 + kk);
      float* o = outF + (size_t)row * D_ + k0 + kk;   // out+1 base: scalar stores
      o[0] = v.x; o[1] = v.y; o[2] = v.z; o[3] = v.w;
      ushort2 p0 = make_ushort2(f2bf(v.x), f2bf(v.y));
      ushort2 p1 = make_ushort2(f2bf(v.z), f2bf(v.w));
      int byte = n * 128 + ((kk * 2) ^ ((n & 7) << 4));
      *(ushort2*)((char*)fs + byte) = p0;
      *(ushort2*)((char*)fs + byte + 4) = p1;
    }
    __syncthreads();
    // compute: wave w owns rows [w*64, w*64+64), all 48 cols
    #pragma unroll
    for (int ks = 0; ks < 2; ks++) {
      int kbyte = (ks * 32 + ((lane >> 4) << 3)) * 2;
      bf16x8 a[4], bb[3];
      #pragma unroll
      for (int mi = 0; mi < 4; mi++) {
        int row = wave * 64 + mi * 16 + (lane & 15);
        a[mi] = *(const bf16x8*)((char*)xs + row * 128 + (kbyte ^ ((row & 7) << 4)));
      }
      #pragma unroll
      for (int ni = 0; ni < 3; ni++) {
        int row = ni * 16 + (lane & 15);
        bb[ni] = *(const bf16x8*)((char*)fs + row * 128 + (kbyte ^ ((row & 7) << 4)));
      }
      #pragma unroll
      for (int mi = 0; mi < 4; mi++)
        #pragma unroll
        for (int ni = 0; ni < 3; ni++)
          acc[mi][ni] = __builtin_amdgcn_mfma_f32_16x16x32_bf16(a[mi], bb[ni], acc[mi][ni], 0, 0, 0);
    }
  }

  // per-row (b) partial max / sumexp over this block's 48 cols
  int g = lane >> 4, c = lane & 15;
  #pragma unroll
  for (int mi = 0; mi < 4; mi++) {
    #pragma unroll
    for (int r = 0; r < 4; r++) {
      float v0 = acc[mi][0][r] * INV_TEMP;
      float v1 = acc[mi][1][r] * INV_TEMP;
      float v2 = acc[mi][2][r] * INV_TEMP;
      float mx = fmaxf(fmaxf(v0, v1), v2);
      #pragma unroll
      for (int m = 8; m >= 1; m >>= 1) mx = fmaxf(mx, __shfl_xor(mx, m, 64));
      float s = __expf(v0 - mx) + __expf(v1 - mx) + __expf(v2 - mx);
      #pragma unroll
      for (int m = 8; m >= 1; m >>= 1) s += __shfl_xor(s, m, 64);
      if (c == 0) {
        int row = wave * 64 + mi * 16 + g * 4 + r;
        pmax[(size_t)blockIdx.x * 256 + row] = mx;
        psum[(size_t)blockIdx.x * 256 + row] = s;
      }
    }
  }
}

// ---------------- Kernel C: exact fp32 target logits ------------------------
__global__ __launch_bounds__(256) void ktdot(const float* __restrict__ feats,
                                             const float* __restrict__ x,
                                             const int* __restrict__ tgt,
                                             float* __restrict__ tdot) {
  int b = blockIdx.x, t = threadIdx.x;
  int y = tgt[b];
  const float* fr = feats + (size_t)y * D_;
  const float* xr = x + (size_t)b * D_;
  float s = 0.f;
  #pragma unroll
  for (int i = 0; i < 8; i++) s += fr[t + i * 256] * xr[t + i * 256];
  float tot = blockReduceSum256(s);
  if (t == 0) tdot[b] = tot * INV_TEMP;
}

// ---------------- Kernel D: combine partials -> loss ------------------------
__global__ __launch_bounds__(256) void kloss(const float* __restrict__ pmax,
                                             const float* __restrict__ psum,
                                             const float* __restrict__ tdot,
                                             float* __restrict__ out) {
  int b = threadIdx.x;
  float m = -INFINITY, s = 0.f;
  for (int t = 0; t < NT; t++) {
    float mt = pmax[(size_t)t * 256 + b];
    float st = psum[(size_t)t * 256 + b];
    if (mt > m) { s = s * __expf(m - mt) + st; m = mt; }
    else        { s += st * __expf(mt - m); }
  }
  float logZ = m + logf(s);
  float lb = logZ - tdot[b];
  float tot = blockReduceSum256(lb);
  if (b == 0) out[0] = tot * (1.0f / 256.0f);
}

// ---------------- Kernel E: momentum update (first-occurrence chains) -------
__global__ __launch_bounds__(256) void kupdate(const float* __restrict__ feats,
                                               const float* __restrict__ x,
                                               const int* __restrict__ tgt,
                                               float* __restrict__ outF) {
  int b = blockIdx.x, t = threadIdx.x;
  int y = tgt[b];
  for (int i = 0; i < b; i++) if (tgt[i] == y) return;  // block-uniform exit
  float f[8];
  #pragma unroll
  for (int i = 0; i < 8; i++) f[i] = feats[(size_t)y * D_ + t + i * 256];
  for (int b2 = b; b2 < B_; b2++) {
    if (tgt[b2] != y) continue;  // block-uniform
    float ss = 0.f;
    #pragma unroll
    for (int i = 0; i < 8; i++) {
      f[i] = MOM * f[i] + (1.0f - MOM) * x[(size_t)b2 * D_ + t + i * 256];
      ss += f[i] * f[i];
    }
    float tot = blockReduceSum256(ss);
    float inv = 1.0f / (sqrtf(tot) + EPSF);
    #pragma unroll
    for (int i = 0; i < 8; i++) f[i] *= inv;
  }
  #pragma unroll
  for (int i = 0; i < 8; i++) outF[(size_t)y * D_ + t + i * 256] = f[i];
}

extern "C" void kernel_launch(void* const* d_in, const int* in_sizes, int n_in,
                              void* d_out, int out_size, void* d_ws, size_t ws_size,
                              hipStream_t stream) {
  const float* inputs = (const float*)d_in[0];
  const float* feats  = (const float*)d_in[1];
  const int*   tgt    = (const int*)d_in[2];
  float* out  = (float*)d_out;
  float* outF = out + 1;  // new_features, N_ x D_, 4-byte aligned only

  char* ws = (char*)d_ws;
  float*          x    = (float*)ws;                                   // 2 MB
  unsigned short* xbf  = (unsigned short*)(ws + (size_t)B_ * D_ * 4);  // 1 MB
  float*          pmax = (float*)(ws + (size_t)B_ * D_ * 4 + (size_t)B_ * D_ * 2);
  float*          psum = pmax + (size_t)NT * 256;
  float*          tdot = psum + (size_t)NT * 256;

  hipLaunchKernelGGL(knorm,   dim3(B_),  dim3(256), 0, stream, inputs, x, xbf);
  hipLaunchKernelGGL(kmain,   dim3(NT),  dim3(256), 0, stream, feats, xbf, outF, pmax, psum);
  hipLaunchKernelGGL(ktdot,   dim3(B_),  dim3(256), 0, stream, feats, x, tgt, tdot);
  hipLaunchKernelGGL(kloss,   dim3(1),   dim3(256), 0, stream, pmax, psum, tdot, out);
  hipLaunchKernelGGL(kupdate, dim3(B_),  dim3(256), 0, stream, feats, x, tgt, outF);
}

// Round 2
// 204.204 us; speedup vs baseline: 1.8273x; 1.8273x over previous
//
#include <hip/hip_runtime.h>
#include <hip/hip_bf16.h>

#define B_ 256
#define D_ 2048
#define N_ 30000
#define INV_TEMP 20.0f
#define MOM 0.2f
#define EPSF 1e-12f
#define BN 48
#define KC 64
#define NT 625   // 30000 / 48

typedef __attribute__((ext_vector_type(8))) short bf16x8;
typedef __attribute__((ext_vector_type(4))) float f32x4;

__device__ __forceinline__ unsigned short f2bf(float f) {
  union { float f; unsigned int u; } v; v.f = f;
  unsigned int u = v.u;
  unsigned int r = (u + 0x7fffu + ((u >> 16) & 1u)) >> 16;
  return (unsigned short)r;
}

__device__ __forceinline__ float blockReduceSum256(float v) {
  __shared__ float red[4];
  #pragma unroll
  for (int m = 32; m >= 1; m >>= 1) v += __shfl_xor(v, m, 64);
  int lane = threadIdx.x & 63, w = threadIdx.x >> 6;
  __syncthreads();
  if (lane == 0) red[w] = v;
  __syncthreads();
  return red[0] + red[1] + red[2] + red[3];
}

// ---------------- Kernel A: normalize inputs, emit fp32 + bf16 copies -------
__global__ __launch_bounds__(256) void knorm(const float* __restrict__ in,
                                             float* __restrict__ x,
                                             unsigned short* __restrict__ xbf) {
  int b = blockIdx.x, t = threadIdx.x;
  const float* row = in + (size_t)b * D_;
  float vals[8]; float ss = 0.f;
  #pragma unroll
  for (int i = 0; i < 8; i++) { float f = row[t + i * 256]; vals[i] = f; ss += f * f; }
  float tot = blockReduceSum256(ss);
  float inv = 1.0f / (sqrtf(tot) + EPSF);
  #pragma unroll
  for (int i = 0; i < 8; i++) {
    float xv = vals[i] * inv;
    x[(size_t)b * D_ + t + i * 256] = xv;
    xbf[(size_t)b * D_ + t + i * 256] = f2bf(xv);
  }
}

// ---------------- Kernel B: bf16 MFMA GEMM + partial logsumexp + bank copy --
__global__ __launch_bounds__(256) void kmain(const float* __restrict__ feats,
                                             const unsigned short* __restrict__ xbf,
                                             float* __restrict__ outF,
                                             float* __restrict__ pmax,
                                             float* __restrict__ psum) {
  __shared__ __align__(16) unsigned short xs[256 * KC];  // 32 KB, swizzled
  __shared__ __align__(16) unsigned short fs[BN * KC];   // 6 KB, swizzled
  int tid = threadIdx.x;
  int wave = tid >> 6, lane = tid & 63;
  int n0 = blockIdx.x * BN;

  f32x4 acc[4][3];
  #pragma unroll
  for (int i = 0; i < 4; i++)
    #pragma unroll
    for (int j = 0; j < 3; j++) acc[i][j] = f32x4{0.f, 0.f, 0.f, 0.f};

  for (int k0 = 0; k0 < D_; k0 += KC) {
    __syncthreads();
    // stage x tile: 256 rows x 64 cols (bf16), 16B per thread-iter
    #pragma unroll
    for (int i = 0; i < 8; i++) {
      int fi = tid + i * 256;
      int b = fi >> 3, g = fi & 7;
      uint4 v = *(const uint4*)(xbf + (size_t)b * D_ + k0 + g * 8);
      int byte = b * 128 + ((g * 16) ^ ((b & 7) << 4));
      *(uint4*)((char*)xs + byte) = v;
    }
    // stage f tile: 48 rows x 64 cols fp32 -> bf16, fused copy to out
    #pragma unroll
    for (int i = 0; i < 3; i++) {
      int fi = tid + i * 256;
      int n = fi >> 4, kk = (fi & 15) * 4;
      int row = n0 + n;
      const float4 v = *(const float4*)(feats + (size_t)row * D_ + k0 + kk);
      float* o = outF + (size_t)row * D_ + k0 + kk;   // out+1 base: scalar stores
      o[0] = v.x; o[1] = v.y; o[2] = v.z; o[3] = v.w;
      ushort2 p0 = make_ushort2(f2bf(v.x), f2bf(v.y));
      ushort2 p1 = make_ushort2(f2bf(v.z), f2bf(v.w));
      int byte = n * 128 + ((kk * 2) ^ ((n & 7) << 4));
      *(ushort2*)((char*)fs + byte) = p0;
      *(ushort2*)((char*)fs + byte + 4) = p1;
    }
    __syncthreads();
    // compute: wave w owns rows [w*64, w*64+64), all 48 cols
    #pragma unroll
    for (int ks = 0; ks < 2; ks++) {
      int kbyte = (ks * 32 + ((lane >> 4) << 3)) * 2;
      bf16x8 a[4], bb[3];
      #pragma unroll
      for (int mi = 0; mi < 4; mi++) {
        int row = wave * 64 + mi * 16 + (lane & 15);
        a[mi] = *(const bf16x8*)((char*)xs + row * 128 + (kbyte ^ ((row & 7) << 4)));
      }
      #pragma unroll
      for (int ni = 0; ni < 3; ni++) {
        int row = ni * 16 + (lane & 15);
        bb[ni] = *(const bf16x8*)((char*)fs + row * 128 + (kbyte ^ ((row & 7) << 4)));
      }
      #pragma unroll
      for (int mi = 0; mi < 4; mi++)
        #pragma unroll
        for (int ni = 0; ni < 3; ni++)
          acc[mi][ni] = __builtin_amdgcn_mfma_f32_16x16x32_bf16(a[mi], bb[ni], acc[mi][ni], 0, 0, 0);
    }
  }

  // per-row (b) partial max / sumexp over this block's 48 cols
  // layout: [row][tile] so the combine kernel reads coalesced
  int g = lane >> 4, c = lane & 15;
  #pragma unroll
  for (int mi = 0; mi < 4; mi++) {
    #pragma unroll
    for (int r = 0; r < 4; r++) {
      float v0 = acc[mi][0][r] * INV_TEMP;
      float v1 = acc[mi][1][r] * INV_TEMP;
      float v2 = acc[mi][2][r] * INV_TEMP;
      float mx = fmaxf(fmaxf(v0, v1), v2);
      #pragma unroll
      for (int m = 8; m >= 1; m >>= 1) mx = fmaxf(mx, __shfl_xor(mx, m, 64));
      float s = __expf(v0 - mx) + __expf(v1 - mx) + __expf(v2 - mx);
      #pragma unroll
      for (int m = 8; m >= 1; m >>= 1) s += __shfl_xor(s, m, 64);
      if (c == 0) {
        int row = wave * 64 + mi * 16 + g * 4 + r;
        pmax[(size_t)row * NT + blockIdx.x] = mx;
        psum[(size_t)row * NT + blockIdx.x] = s;
      }
    }
  }
}

// ---------------- Kernel C: exact fp32 target logits ------------------------
__global__ __launch_bounds__(256) void ktdot(const float* __restrict__ feats,
                                             const float* __restrict__ x,
                                             const int* __restrict__ tgt,
                                             float* __restrict__ tdot) {
  int b = blockIdx.x, t = threadIdx.x;
  int y = tgt[b];
  const float* fr = feats + (size_t)y * D_;
  const float* xr = x + (size_t)b * D_;
  float s = 0.f;
  #pragma unroll
  for (int i = 0; i < 8; i++) s += fr[t + i * 256] * xr[t + i * 256];
  float tot = blockReduceSum256(s);
  if (t == 0) tdot[b] = tot * INV_TEMP;
}

// ---------------- Kernel D1: per-row logsumexp combine (256 blocks) ---------
__global__ __launch_bounds__(256) void kloss1(const float* __restrict__ pmax,
                                              const float* __restrict__ psum,
                                              const float* __restrict__ tdot,
                                              float* __restrict__ lb) {
  int b = blockIdx.x, t = threadIdx.x;
  float m = -INFINITY, s = 0.f;
  for (int i = t; i < NT; i += 256) {
    float mt = pmax[(size_t)b * NT + i];
    float st = psum[(size_t)b * NT + i];
    if (mt > m) { s = s * __expf(m - mt) + st; m = mt; }
    else        { s += st * __expf(mt - m); }
  }
  // merge (m,s) across 64 lanes
  #pragma unroll
  for (int w = 32; w >= 1; w >>= 1) {
    float mo = __shfl_xor(m, w, 64);
    float so = __shfl_xor(s, w, 64);
    float M = fmaxf(m, mo);
    s = s * __expf(m - M) + so * __expf(mo - M);
    m = M;
  }
  __shared__ float sm[4], ssum[4];
  int lane = t & 63, w = t >> 6;
  if (lane == 0) { sm[w] = m; ssum[w] = s; }
  __syncthreads();
  if (t == 0) {
    float M = fmaxf(fmaxf(sm[0], sm[1]), fmaxf(sm[2], sm[3]));
    float S = ssum[0] * __expf(sm[0] - M) + ssum[1] * __expf(sm[1] - M) +
              ssum[2] * __expf(sm[2] - M) + ssum[3] * __expf(sm[3] - M);
    lb[b] = M + logf(S) - tdot[b];
  }
}

// ---------------- Kernel D2: mean over batch -> loss ------------------------
__global__ __launch_bounds__(256) void kloss2(const float* __restrict__ lb,
                                              float* __restrict__ out) {
  int t = threadIdx.x;
  float tot = blockReduceSum256(lb[t]);
  if (t == 0) out[0] = tot * (1.0f / 256.0f);
}

// ---------------- Kernel E: momentum update (first-occurrence chains) -------
__global__ __launch_bounds__(256) void kupdate(const float* __restrict__ feats,
                                               const float* __restrict__ x,
                                               const int* __restrict__ tgt,
                                               float* __restrict__ outF) {
  int b = blockIdx.x, t = threadIdx.x;
  int y = tgt[b];
  for (int i = 0; i < b; i++) if (tgt[i] == y) return;  // block-uniform exit
  float f[8];
  #pragma unroll
  for (int i = 0; i < 8; i++) f[i] = feats[(size_t)y * D_ + t + i * 256];
  for (int b2 = b; b2 < B_; b2++) {
    if (tgt[b2] != y) continue;  // block-uniform
    float ss = 0.f;
    #pragma unroll
    for (int i = 0; i < 8; i++) {
      f[i] = MOM * f[i] + (1.0f - MOM) * x[(size_t)b2 * D_ + t + i * 256];
      ss += f[i] * f[i];
    }
    float tot = blockReduceSum256(ss);
    float inv = 1.0f / (sqrtf(tot) + EPSF);
    #pragma unroll
    for (int i = 0; i < 8; i++) f[i] *= inv;
  }
  #pragma unroll
  for (int i = 0; i < 8; i++) outF[(size_t)y * D_ + t + i * 256] = f[i];
}

extern "C" void kernel_launch(void* const* d_in, const int* in_sizes, int n_in,
                              void* d_out, int out_size, void* d_ws, size_t ws_size,
                              hipStream_t stream) {
  const float* inputs = (const float*)d_in[0];
  const float* feats  = (const float*)d_in[1];
  const int*   tgt    = (const int*)d_in[2];
  float* out  = (float*)d_out;
  float* outF = out + 1;  // new_features, N_ x D_, 4-byte aligned only

  char* ws = (char*)d_ws;
  float*          x    = (float*)ws;                                   // 2 MB
  unsigned short* xbf  = (unsigned short*)(ws + (size_t)B_ * D_ * 4);  // 1 MB
  float*          pmax = (float*)(ws + (size_t)B_ * D_ * 4 + (size_t)B_ * D_ * 2);
  float*          psum = pmax + (size_t)B_ * NT;
  float*          tdot = psum + (size_t)B_ * NT;
  float*          lb   = tdot + B_;

  hipLaunchKernelGGL(knorm,   dim3(B_),  dim3(256), 0, stream, inputs, x, xbf);
  hipLaunchKernelGGL(kmain,   dim3(NT),  dim3(256), 0, stream, feats, xbf, outF, pmax, psum);
  hipLaunchKernelGGL(ktdot,   dim3(B_),  dim3(256), 0, stream, feats, x, tgt, tdot);
  hipLaunchKernelGGL(kloss1,  dim3(B_),  dim3(256), 0, stream, pmax, psum, tdot, lb);
  hipLaunchKernelGGL(kloss2,  dim3(1),   dim3(256), 0, stream, lb, out);
  hipLaunchKernelGGL(kupdate, dim3(B_),  dim3(256), 0, stream, feats, x, tgt, outF);
}